// Round 18
// baseline (101.503 us; speedup 1.0000x reference)
//
#include <hip/hip_runtime.h>
#include <hip/hip_bf16.h>

typedef __bf16 bf16_t;
typedef __bf16 bf16x8 __attribute__((ext_vector_type(8)));
typedef __bf16 bf16x4 __attribute__((ext_vector_type(4)));
typedef float  f32x4  __attribute__((ext_vector_type(4)));

#define B_   2
#define S_   2048
#define D_   1024
#define H_   16
#define HD_  64
#define HW   32
#define SCALE_ 0.125f

__device__ __forceinline__ void gl_lds16(const bf16_t* g, bf16_t* l) {
  __builtin_amdgcn_global_load_lds(
      (const __attribute__((address_space(1))) void*)g,
      (__attribute__((address_space(3))) void*)l, 16, 0, 0);
}

// ------------- convert + transpose weights only: W[k][n] fp32 -> Wt[p][n][k] bf16
__global__ __launch_bounds__(256) void k_convw(const float* __restrict__ W0,
                                               const float* __restrict__ W1,
                                               const float* __restrict__ W2,
                                               const float* __restrict__ W3,
                                               bf16_t* __restrict__ Wt) {
  __shared__ bf16_t t[64][72];
  int bid = blockIdx.x;
  int tid = threadIdx.x;
  int wsel = bid >> 8;
  const float* W = (wsel == 0) ? W0 : (wsel == 1) ? W1 : (wsel == 2) ? W2 : W3;
  bf16_t* dst = Wt + (size_t)wsel * D_ * D_;
  int tile = bid & 255;
  int k0 = (tile >> 4) * 64, n0 = (tile & 15) * 64;
  int r = tid >> 4, c4 = (tid & 15) * 4;
#pragma unroll
  for (int i = 0; i < 4; ++i) {
    int row = i * 16 + r;
    float4 v = *(const float4*)(W + (size_t)(k0 + row) * D_ + n0 + c4);
    t[row][c4 + 0] = (bf16_t)v.x;
    t[row][c4 + 1] = (bf16_t)v.y;
    t[row][c4 + 2] = (bf16_t)v.z;
    t[row][c4 + 3] = (bf16_t)v.w;
  }
  __syncthreads();
#pragma unroll
  for (int i = 0; i < 4; ++i) {
    int row = i * 16 + r;
    bf16x4 o;
    o[0] = t[c4 + 0][row];
    o[1] = t[c4 + 1][row];
    o[2] = t[c4 + 2][row];
    o[3] = t[c4 + 3][row];
    *(bf16x4*)(dst + (size_t)(n0 + row) * D_ + k0 + c4) = o;
  }
}

// ---- QKV GEMM: r17 loop + fused fp32-A staging (T14 issue-early/write-late).
// A reg-staged from fp32 X (cvt in-kernel, replaces the x-convert kernel);
// B via global_load_lds. Ring-3 LDS, counted vmcnt(6), conflict-free chunk-XOR.
// Ledger: step t: ds_write A(t+1) (regs loaded at t-1; data-dep drains loads);
// issue A(t+2) reg-loads + B(t+2) gl_lds; MFMA buf[t%3]; vmcnt(6) drains B(t+1)
// (older than t+2's 6 ops); lgkmcnt(0) flushes ds_writes; barrier.
__global__ __launch_bounds__(256) void k_gemm_qkv(const float* __restrict__ Xf,
                                                  const bf16_t* __restrict__ Wt,
                                                  bf16_t* __restrict__ Q,
                                                  bf16_t* __restrict__ Kb,
                                                  bf16_t* __restrict__ V) {
  __shared__ bf16_t sA[3 * 128 * 32];   // 24 KB
  __shared__ bf16_t sB[3 * 128 * 32];   // 24 KB  -> 3 blocks/CU
  int bid = blockIdx.x;
  int mt = bid & 31, nt = bid >> 5;
  int wsel = nt >> 3;
  int n0 = (nt & 7) * 128, m0 = mt * 128;
  const bf16_t* Wp = Wt + (size_t)wsel * D_ * D_;
  int tid = threadIdx.x, lane = tid & 63, wave = tid >> 6;
  int wr = (wave >> 1) * 64, wc = (wave & 1) * 64;
  int r0 = wave * 32 + (lane >> 2);
  int ce = (((lane & 3) ^ ((lane >> 3) & 3))) * 8;  // pre-swizzled source chunk
  const float*  gA0f = Xf + (size_t)(m0 + r0) * D_ + ce;
  const bf16_t* gB0  = Wp + (size_t)(n0 + r0) * D_ + ce;
  int lofs = wave * 1024;
  int lane8 = lane * 8;
  f32x4 acc[4][4] = {};
  int rl = lane & 15, hi = lane >> 4;
  int cofs = (hi ^ ((rl >> 1) & 3)) * 8;
  // ---------- prologue ----------
  // B(0) first (oldest), then A(0) direct, then A(1) regs + B(1)
  gl_lds16(gB0, sB + lofs);
  gl_lds16(gB0 + (size_t)16 * D_, sB + lofs + 512);
  {
    float4 x0 = *(const float4*)(gA0f);
    float4 x1 = *(const float4*)(gA0f + 4);
    float4 x2 = *(const float4*)(gA0f + (size_t)16 * D_);
    float4 x3 = *(const float4*)(gA0f + (size_t)16 * D_ + 4);
    bf16x8 va, vb;
    va[0] = (bf16_t)x0.x; va[1] = (bf16_t)x0.y; va[2] = (bf16_t)x0.z; va[3] = (bf16_t)x0.w;
    va[4] = (bf16_t)x1.x; va[5] = (bf16_t)x1.y; va[6] = (bf16_t)x1.z; va[7] = (bf16_t)x1.w;
    vb[0] = (bf16_t)x2.x; vb[1] = (bf16_t)x2.y; vb[2] = (bf16_t)x2.z; vb[3] = (bf16_t)x2.w;
    vb[4] = (bf16_t)x3.x; vb[5] = (bf16_t)x3.y; vb[6] = (bf16_t)x3.z; vb[7] = (bf16_t)x3.w;
    *(bf16x8*)(sA + lofs + lane8) = va;
    *(bf16x8*)(sA + lofs + 512 + lane8) = vb;
  }
  float4 aR0 = *(const float4*)(gA0f + 32);
  float4 aR1 = *(const float4*)(gA0f + 36);
  float4 aR2 = *(const float4*)(gA0f + 32 + (size_t)16 * D_);
  float4 aR3 = *(const float4*)(gA0f + 36 + (size_t)16 * D_);
  gl_lds16(gB0 + 32, sB + 4096 + lofs);
  gl_lds16(gB0 + 32 + (size_t)16 * D_, sB + 4096 + lofs + 512);
  asm volatile("s_waitcnt vmcnt(6)" ::: "memory");   // B(0) landed (cvt drained x's)
  asm volatile("s_waitcnt lgkmcnt(0)" ::: "memory"); // A(0) ds_writes visible
  __builtin_amdgcn_sched_barrier(0);
  __builtin_amdgcn_s_barrier();
  asm volatile("" ::: "memory");
  // ---------- main loop ----------
  int cur = 0;
  for (int t = 0; t < 32; ++t) {
    int wnext = cur + 1; if (wnext >= 3) wnext -= 3;
    int sb = cur + 2; if (sb >= 3) sb -= 3;
    if (t + 1 < 32) {   // ds_write A(t+1) from regs (auto-drains their loads)
      bf16x8 va, vb;
      va[0] = (bf16_t)aR0.x; va[1] = (bf16_t)aR0.y; va[2] = (bf16_t)aR0.z; va[3] = (bf16_t)aR0.w;
      va[4] = (bf16_t)aR1.x; va[5] = (bf16_t)aR1.y; va[6] = (bf16_t)aR1.z; va[7] = (bf16_t)aR1.w;
      vb[0] = (bf16_t)aR2.x; vb[1] = (bf16_t)aR2.y; vb[2] = (bf16_t)aR2.z; vb[3] = (bf16_t)aR2.w;
      vb[4] = (bf16_t)aR3.x; vb[5] = (bf16_t)aR3.y; vb[6] = (bf16_t)aR3.z; vb[7] = (bf16_t)aR3.w;
      *(bf16x8*)(sA + wnext * 4096 + lofs + lane8) = va;
      *(bf16x8*)(sA + wnext * 4096 + lofs + 512 + lane8) = vb;
    }
    if (t + 2 < 32) {   // issue t+2: 4 A reg-loads + 2 B gl_lds (6 vm ops)
      int kt2 = (t + 2) * 32;
      aR0 = *(const float4*)(gA0f + kt2);
      aR1 = *(const float4*)(gA0f + kt2 + 4);
      aR2 = *(const float4*)(gA0f + kt2 + (size_t)16 * D_);
      aR3 = *(const float4*)(gA0f + kt2 + (size_t)16 * D_ + 4);
      gl_lds16(gB0 + kt2, sB + sb * 4096 + lofs);
      gl_lds16(gB0 + kt2 + (size_t)16 * D_, sB + sb * 4096 + lofs + 512);
    }
    const bf16_t* pA = sA + cur * 4096;
    const bf16_t* pB = sB + cur * 4096;
    bf16x8 af[4], bfr[4];
#pragma unroll
    for (int m = 0; m < 4; ++m)
      af[m] = *(const bf16x8*)&pA[(wr + m * 16 + rl) * 32 + cofs];
#pragma unroll
    for (int n = 0; n < 4; ++n)
      bfr[n] = *(const bf16x8*)&pB[(wc + n * 16 + rl) * 32 + cofs];
    __builtin_amdgcn_s_setprio(1);
#pragma unroll
    for (int m = 0; m < 4; ++m)
#pragma unroll
      for (int n = 0; n < 4; ++n)
        acc[m][n] = __builtin_amdgcn_mfma_f32_16x16x32_bf16(af[m], bfr[n], acc[m][n], 0, 0, 0);
    __builtin_amdgcn_s_setprio(0);
    if (t <= 29) {
      asm volatile("s_waitcnt vmcnt(6)" ::: "memory");  // drains B(t+1)
    } else if (t == 30) {
      asm volatile("s_waitcnt vmcnt(0)" ::: "memory");  // drains B(31)
    }
    asm volatile("s_waitcnt lgkmcnt(0)" ::: "memory");  // ds_writes visible
    if (t < 31) {
      __builtin_amdgcn_sched_barrier(0);
      __builtin_amdgcn_s_barrier();
      asm volatile("" ::: "memory");
    }
    cur = wnext;
  }
  // ---------- epilogue ----------
  if (wsel < 2) {
    float qscale = (wsel == 0) ? SCALE_ : 1.0f;
    bf16_t* Dst = wsel ? Kb : Q;
#pragma unroll
    for (int m = 0; m < 4; ++m) {
#pragma unroll
      for (int n = 0; n < 4; ++n) {
#pragma unroll
        for (int r = 0; r < 4; ++r) {
          int gm = m0 + wr + m * 16 + hi * 4 + r;
          int gn = n0 + wc + n * 16 + rl;
          int b = gm >> 11, s = gm & 2047;
          int h = gn >> 6, hd = gn & 63;
          Dst[(((size_t)(b * H_ + h)) * S_ + s) * HD_ + hd] = (bf16_t)(acc[m][n][r] * qscale);
        }
      }
    }
  } else {
    bf16_t* bounce = sA;   // 24KB free; need 64*136*2 = 17.4KB
#pragma unroll
    for (int hh = 0; hh < 2; ++hh) {
      __syncthreads();
      if ((wave & 1) == hh) {
#pragma unroll
        for (int m = 0; m < 4; ++m)
#pragma unroll
          for (int n = 0; n < 4; ++n)
#pragma unroll
            for (int r = 0; r < 4; ++r)
              bounce[(n * 16 + rl) * 136 + wr + m * 16 + hi * 4 + r] = (bf16_t)acc[m][n][r];
      }
      __syncthreads();
#pragma unroll
      for (int ps = 0; ps < 4; ++ps) {
        int idx = ps * 256 + tid;
        int row = idx >> 4, c8 = (idx & 15) * 8;
        bf16x8 v = *(const bf16x8*)&bounce[row * 136 + c8];
        int gn = n0 + hh * 64 + row;
        int h = gn >> 6, hd = gn & 63;
        int gmS = m0 + c8;
        int b2 = gmS >> 11, s0 = gmS & 2047;
        *(bf16x8*)&V[(((size_t)(b2 * H_ + h)) * HD_ + hd) * S_ + s0] = v;
      }
    }
  }
}

// ---- out GEMM: 64x128 tile, BK=32, 2-barrier (r17) ----
__global__ __launch_bounds__(256) void k_gemm_out(const bf16_t* __restrict__ A,
                                                  const bf16_t* __restrict__ Wp,
                                                  const float* __restrict__ bo,
                                                  float* __restrict__ out) {
  __shared__ bf16_t sA[64 * 32];
  __shared__ bf16_t sB[128 * 32];
  int bid = blockIdx.x;
  int mt = bid & 63, nt = bid >> 6;
  int n0 = nt * 128, m0 = mt * 64;
  int tid = threadIdx.x, lane = tid & 63, wave = tid >> 6;
  int wc = wave * 32;
  int crow = lane >> 2, ccol = (lane & 3) * 8;
  const bf16_t* gsrc0; bf16_t* ldst0;
  const bf16_t* gsrc1; bf16_t* ldst1;
  const bf16_t* gsrc2; bf16_t* ldst2;
#pragma unroll
  for (int j = 0; j < 3; ++j) {
    int c = wave * 3 + j;
    const bf16_t* g; bf16_t* l;
    if (c < 4) {
      g = A + (size_t)(m0 + c * 16 + crow) * D_ + ccol;
      l = sA + c * 512;
    } else {
      g = Wp + (size_t)(n0 + (c - 4) * 16 + crow) * D_ + ccol;
      l = sB + (c - 4) * 512;
    }
    if (j == 0) { gsrc0 = g; ldst0 = l; }
    else if (j == 1) { gsrc1 = g; ldst1 = l; }
    else { gsrc2 = g; ldst2 = l; }
  }
  f32x4 acc[4][2] = {};
  int kq = (lane >> 4) * 8, rl = lane & 15, hi = lane >> 4;
  for (int kt = 0; kt < D_; kt += 32) {
    __syncthreads();
    gl_lds16(gsrc0 + kt, ldst0);
    gl_lds16(gsrc1 + kt, ldst1);
    gl_lds16(gsrc2 + kt, ldst2);
    __syncthreads();
    bf16x8 af[4], bfr[2];
#pragma unroll
    for (int m = 0; m < 4; ++m)
      af[m] = *(const bf16x8*)&sA[(m * 16 + rl) * 32 + kq];
#pragma unroll
    for (int n = 0; n < 2; ++n)
      bfr[n] = *(const bf16x8*)&sB[(wc + n * 16 + rl) * 32 + kq];
#pragma unroll
    for (int m = 0; m < 4; ++m)
#pragma unroll
      for (int n = 0; n < 2; ++n)
        acc[m][n] = __builtin_amdgcn_mfma_f32_16x16x32_bf16(af[m], bfr[n], acc[m][n], 0, 0, 0);
  }
#pragma unroll
  for (int m = 0; m < 4; ++m) {
#pragma unroll
    for (int n = 0; n < 2; ++n) {
#pragma unroll
      for (int r = 0; r < 4; ++r) {
        int gm = m0 + m * 16 + hi * 4 + r;
        int gn = n0 + wc + n * 16 + rl;
        out[(size_t)gm * D_ + gn] = acc[m][n][r] + bo[gn];
      }
    }
  }
}

// ---------------- MFMA local causal attention: QB=128 (r17) ----------------
#define QB 128
#define KW 160
#define VW 176
#define KLP 68
#define VTP 180

__global__ __launch_bounds__(256) void k_attn(const bf16_t* __restrict__ Q,
                                              const bf16_t* __restrict__ K,
                                              const bf16_t* __restrict__ Vt,
                                              bf16_t* __restrict__ O) {
  __shared__ bf16_t sK[KW][KLP];
  __shared__ bf16_t sV[HD_][VTP];
  __shared__ bf16_t sP[4][16][KLP];
  int bid = blockIdx.x;
  int qb = bid & 15, bh = bid >> 4;
  int q0 = qb * QB;
  const bf16_t* Kp = K + (size_t)bh * S_ * HD_;
  const bf16_t* Vp = Vt + (size_t)bh * HD_ * S_;
  const bf16_t* Qp = Q + (size_t)bh * S_ * HD_;
  int tid = threadIdx.x;
  int lane = tid & 63, wave = tid >> 6;
  int rl = lane & 15, hi = lane >> 4;
  int wk0b = q0 - HW;
  for (int idx = tid; idx < KW * 8; idx += 256) {
    int row = idx >> 3, c8 = (idx & 7) * 8;
    int kg = wk0b + row;
    kg = kg < 0 ? 0 : (kg > S_ - 1 ? S_ - 1 : kg);
    *(bf16x8*)&sK[row][c8] = *(const bf16x8*)(Kp + (size_t)kg * HD_ + c8);
  }
  for (int idx = tid; idx < HD_ * (VW / 8); idx += 256) {
    int row = idx / (VW / 8), c8 = (idx % (VW / 8)) * 8;
    int ks = wk0b + c8;
    ks = ks < 0 ? 0 : (ks > S_ - 8 ? S_ - 8 : ks);
    *(bf16x8*)&sV[row][c8] = *(const bf16x8*)(Vp + (size_t)row * S_ + ks);
  }
  __syncthreads();
  int b = bh >> 4, h = bh & 15;
#pragma unroll
  for (int qi = 0; qi < 2; ++qi) {
    int wko = qi * 64 + wave * 16;
    bf16x8 qf0 = *(const bf16x8*)(Qp + (size_t)(q0 + wko + rl) * HD_ + hi * 8);
    bf16x8 qf1 = *(const bf16x8*)(Qp + (size_t)(q0 + wko + rl) * HD_ + 32 + hi * 8);
    f32x4 accs[3] = {};
#pragma unroll
    for (int kb = 0; kb < 3; ++kb) {
      bf16x8 kf = *(const bf16x8*)&sK[wko + kb * 16 + rl][hi * 8];
      accs[kb] = __builtin_amdgcn_mfma_f32_16x16x32_bf16(kf, qf0, accs[kb], 0, 0, 0);
    }
#pragma unroll
    for (int kb = 0; kb < 3; ++kb) {
      bf16x8 kf = *(const bf16x8*)&sK[wko + kb * 16 + rl][32 + hi * 8];
      accs[kb] = __builtin_amdgcn_mfma_f32_16x16x32_bf16(kf, qf1, accs[kb], 0, 0, 0);
    }
    float p[3][4];
    float mx = -1e30f;
#pragma unroll
    for (int kb = 0; kb < 3; ++kb) {
#pragma unroll
      for (int r = 0; r < 4; ++r) {
        int kl = kb * 16 + hi * 4 + r;
        bool valid = (kl >= rl) && (kl <= rl + HW) && (wk0b + wko + kl >= 0);
        float s = valid ? accs[kb][r] : -1e30f;
        p[kb][r] = s;
        mx = fmaxf(mx, s);
      }
    }
    mx = fmaxf(mx, __shfl_xor(mx, 16));
    mx = fmaxf(mx, __shfl_xor(mx, 32));
    float sum = 0.f;
#pragma unroll
    for (int kb = 0; kb < 3; ++kb)
#pragma unroll
      for (int r = 0; r < 4; ++r) {
        p[kb][r] = __expf(p[kb][r] - mx);
        sum += p[kb][r];
      }
    sum += __shfl_xor(sum, 16);
    sum += __shfl_xor(sum, 32);
    float inv = 1.f / sum;
#pragma unroll
    for (int kb = 0; kb < 3; ++kb) {
      bf16x4 pv;
#pragma unroll
      for (int r = 0; r < 4; ++r) pv[r] = (bf16_t)(p[kb][r] * inv);
      *(bf16x4*)&sP[wave][rl][kb * 16 + hi * 4] = pv;
    }
    {
      bf16x4 z4;
#pragma unroll
      for (int r = 0; r < 4; ++r) z4[r] = (bf16_t)0.f;
      *(bf16x4*)&sP[wave][rl][48 + hi * 4] = z4;
    }
    f32x4 acco[4] = {};
#pragma unroll
    for (int ks = 0; ks < 2; ++ks) {
      bf16x8 aP = *(const bf16x8*)&sP[wave][rl][ks * 32 + hi * 8];
#pragma unroll
      for (int n = 0; n < 4; ++n) {
        bf16x8 bV = *(const bf16x8*)&sV[n * 16 + rl][wko + ks * 32 + hi * 8];
        acco[n] = __builtin_amdgcn_mfma_f32_16x16x32_bf16(aP, bV, acco[n], 0, 0, 0);
      }
    }
#pragma unroll
    for (int n = 0; n < 4; ++n) {
#pragma unroll
      for (int r = 0; r < 4; ++r) {
        int qgl = q0 + wko + hi * 4 + r;
        int d = n * 16 + rl;
        O[((size_t)(b * S_ + qgl)) * D_ + h * HD_ + d] = (bf16_t)acco[n][r];
      }
    }
  }
}

extern "C" void kernel_launch(void* const* d_in, const int* in_sizes, int n_in,
                              void* d_out, int out_size, void* d_ws, size_t ws_size,
                              hipStream_t stream) {
  const float* x  = (const float*)d_in[0];
  const float* Wq = (const float*)d_in[1];
  const float* Wk = (const float*)d_in[2];
  const float* Wv = (const float*)d_in[3];
  const float* Wo = (const float*)d_in[4];
  const float* bo = (const float*)d_in[5];
  float* out = (float*)d_out;
  char* ws = (char*)d_ws;
  bf16_t* wt = (bf16_t*)(ws + (size_t)(8 << 20));   // 8 MB [4][1024][1024]
  bf16_t* qb = (bf16_t*)(ws + (size_t)(16 << 20));  // 8 MB [bh][s][64]
  bf16_t* kb = (bf16_t*)(ws + (size_t)(24 << 20));  // 8 MB [bh][s][64]
  bf16_t* vb = (bf16_t*)(ws + (size_t)(32 << 20));  // 8 MB [bh][64][s] (transposed)
  bf16_t* ob = (bf16_t*)(ws + (size_t)(40 << 20));  // 8 MB [b][s][1024]

  hipLaunchKernelGGL(k_convw, dim3(1024), dim3(256), 0, stream,
                     Wq, Wk, Wv, Wo, wt);
  hipLaunchKernelGGL(k_gemm_qkv, dim3(768), dim3(256), 0, stream, x, wt, qb, kb, vb);
  hipLaunchKernelGGL(k_attn, dim3(512), dim3(256), 0, stream, qb, kb, vb, ob);
  hipLaunchKernelGGL(k_gemm_out, dim3(512), dim3(256), 0, stream,
                     ob, wt + (size_t)3 * D_ * D_, bo, out);
}

// Round 19
// 79.705 us; speedup vs baseline: 1.2735x; 1.2735x over previous
//
#include <hip/hip_runtime.h>
#include <hip/hip_bf16.h>

typedef __bf16 bf16_t;
typedef __bf16 bf16x8 __attribute__((ext_vector_type(8)));
typedef __bf16 bf16x4 __attribute__((ext_vector_type(4)));
typedef float  f32x4  __attribute__((ext_vector_type(4)));

#define B_   2
#define S_   2048
#define D_   1024
#define H_   16
#define HD_  64
#define HW   32
#define SCALE_ 0.125f

__device__ __forceinline__ void gl_lds16(const bf16_t* g, bf16_t* l) {
  __builtin_amdgcn_global_load_lds(
      (const __attribute__((address_space(1))) void*)g,
      (__attribute__((address_space(3))) void*)l, 16, 0, 0);
}

// ------------- fused converts: x fp32->bf16 (blocks 0..2047), W transpose (2048..3071)
__global__ __launch_bounds__(256) void k_conv(const float* __restrict__ X,
                                              const float* __restrict__ W0,
                                              const float* __restrict__ W1,
                                              const float* __restrict__ W2,
                                              const float* __restrict__ W3,
                                              bf16_t* __restrict__ Xb,
                                              bf16_t* __restrict__ Wt) {
  __shared__ bf16_t t[64][72];
  int bid = blockIdx.x;
  int tid = threadIdx.x;
  if (bid < 2048) {
    int i = bid * 256 + tid;
    const float4 a = ((const float4*)X)[i * 2];
    const float4 b = ((const float4*)X)[i * 2 + 1];
    bf16x8 r;
    r[0] = (bf16_t)a.x; r[1] = (bf16_t)a.y; r[2] = (bf16_t)a.z; r[3] = (bf16_t)a.w;
    r[4] = (bf16_t)b.x; r[5] = (bf16_t)b.y; r[6] = (bf16_t)b.z; r[7] = (bf16_t)b.w;
    ((bf16x8*)Xb)[i] = r;
    return;
  }
  int wb = bid - 2048;
  int wsel = wb >> 8;
  const float* W = (wsel == 0) ? W0 : (wsel == 1) ? W1 : (wsel == 2) ? W2 : W3;
  bf16_t* dst = Wt + (size_t)wsel * D_ * D_;
  int tile = wb & 255;
  int k0 = (tile >> 4) * 64, n0 = (tile & 15) * 64;
  int r = tid >> 4, c4 = (tid & 15) * 4;
#pragma unroll
  for (int i = 0; i < 4; ++i) {
    int row = i * 16 + r;
    float4 v = *(const float4*)(W + (size_t)(k0 + row) * D_ + n0 + c4);
    t[row][c4 + 0] = (bf16_t)v.x;
    t[row][c4 + 1] = (bf16_t)v.y;
    t[row][c4 + 2] = (bf16_t)v.z;
    t[row][c4 + 3] = (bf16_t)v.w;
  }
  __syncthreads();
#pragma unroll
  for (int i = 0; i < 4; ++i) {
    int row = i * 16 + r;
    bf16x4 o;
    o[0] = t[c4 + 0][row];
    o[1] = t[c4 + 1][row];
    o[2] = t[c4 + 2][row];
    o[3] = t[c4 + 3][row];
    *(bf16x4*)(dst + (size_t)(n0 + row) * D_ + k0 + c4) = o;
  }
}

// ---- QKV GEMM: r16 loop (128x128, BK=32, triple-buffer counted-vmcnt,
// conflict-free chunk-XOR swizzle) + V-epilogue LDS bounce (coalesced stores).
__global__ __launch_bounds__(256) void k_gemm_qkv(const bf16_t* __restrict__ X,
                                                  const bf16_t* __restrict__ Wt,
                                                  bf16_t* __restrict__ Q,
                                                  bf16_t* __restrict__ Kb,
                                                  bf16_t* __restrict__ V) {
  __shared__ bf16_t sA[3 * 128 * 32];   // 24 KB
  __shared__ bf16_t sB[3 * 128 * 32];   // 24 KB  -> 3 blocks/CU
  int bid = blockIdx.x;
  int mt = bid & 31, nt = bid >> 5;     // XCD = mt%8: 1MB A + 2MB B per XCD L2
  int wsel = nt >> 3;
  int n0 = (nt & 7) * 128, m0 = mt * 128;
  const bf16_t* Wp = Wt + (size_t)wsel * D_ * D_;
  int tid = threadIdx.x, lane = tid & 63, wave = tid >> 6;
  int wr = (wave >> 1) * 64, wc = (wave & 1) * 64;
  int r0 = wave * 32 + (lane >> 2);
  int ce = (((lane & 3) ^ ((lane >> 3) & 3))) * 8;  // pre-swizzled source chunk
  const bf16_t* gA0 = X + (size_t)(m0 + r0) * D_ + ce;
  const bf16_t* gB0 = Wp + (size_t)(n0 + r0) * D_ + ce;
  int lofs = wave * 1024;
#define QSTAGE_(bi, kt) do { \
    gl_lds16(gA0 + (kt), sA + (bi) * 4096 + lofs);        \
    gl_lds16(gA0 + (kt) + (size_t)16 * D_, sA + (bi) * 4096 + lofs + 512); \
    gl_lds16(gB0 + (kt), sB + (bi) * 4096 + lofs);        \
    gl_lds16(gB0 + (kt) + (size_t)16 * D_, sB + (bi) * 4096 + lofs + 512); \
  } while (0)
  f32x4 acc[4][4] = {};
  int rl = lane & 15, hi = lane >> 4;
  int cofs = (hi ^ ((rl >> 1) & 3)) * 8;   // swizzled fragment chunk offset
  QSTAGE_(0, 0);
  QSTAGE_(1, 32);
  asm volatile("s_waitcnt vmcnt(4)" ::: "memory");
  __builtin_amdgcn_sched_barrier(0);
  __builtin_amdgcn_s_barrier();
  asm volatile("" ::: "memory");
  int cur = 0;
  for (int t = 0; t < 32; ++t) {
    const bf16_t* pA = sA + cur * 4096;
    const bf16_t* pB = sB + cur * 4096;
    bf16x8 af[4], bfr[4];
#pragma unroll
    for (int m = 0; m < 4; ++m)
      af[m] = *(const bf16x8*)&pA[(wr + m * 16 + rl) * 32 + cofs];
#pragma unroll
    for (int n = 0; n < 4; ++n)
      bfr[n] = *(const bf16x8*)&pB[(wc + n * 16 + rl) * 32 + cofs];
    int sb = cur + 2; if (sb >= 3) sb -= 3;
    if (t + 2 < 32) QSTAGE_(sb, (t + 2) * 32);
    __builtin_amdgcn_s_setprio(1);
#pragma unroll
    for (int m = 0; m < 4; ++m)
#pragma unroll
      for (int n = 0; n < 4; ++n)
        acc[m][n] = __builtin_amdgcn_mfma_f32_16x16x32_bf16(af[m], bfr[n], acc[m][n], 0, 0, 0);
    __builtin_amdgcn_s_setprio(0);
    if (t < 30) {
      asm volatile("s_waitcnt vmcnt(4)" ::: "memory");
    } else if (t == 30) {
      asm volatile("s_waitcnt vmcnt(0)" ::: "memory");
    }
    if (t < 31) {
      __builtin_amdgcn_sched_barrier(0);
      __builtin_amdgcn_s_barrier();
      asm volatile("" ::: "memory");
    }
    if (++cur == 3) cur = 0;
  }
#undef QSTAGE_
  if (wsel < 2) {
    float qscale = (wsel == 0) ? SCALE_ : 1.0f;
    bf16_t* Dst = wsel ? Kb : Q;
#pragma unroll
    for (int m = 0; m < 4; ++m) {
#pragma unroll
      for (int n = 0; n < 4; ++n) {
#pragma unroll
        for (int r = 0; r < 4; ++r) {
          int gm = m0 + wr + m * 16 + hi * 4 + r;
          int gn = n0 + wc + n * 16 + rl;
          int b = gm >> 11, s = gm & 2047;
          int h = gn >> 6, hd = gn & 63;
          Dst[(((size_t)(b * H_ + h)) * S_ + s) * HD_ + hd] = (bf16_t)(acc[m][n][r] * qscale);
        }
      }
    }
  } else {
    // V: transpose via LDS bounce -> coalesced 16B stores along s
    bf16_t* bounce = sA;   // 24KB free; need 64*136*2 = 17.4KB
#pragma unroll
    for (int hh = 0; hh < 2; ++hh) {
      __syncthreads();
      if ((wave & 1) == hh) {
#pragma unroll
        for (int m = 0; m < 4; ++m)
#pragma unroll
          for (int n = 0; n < 4; ++n)
#pragma unroll
            for (int r = 0; r < 4; ++r)
              bounce[(n * 16 + rl) * 136 + wr + m * 16 + hi * 4 + r] = (bf16_t)acc[m][n][r];
      }
      __syncthreads();
#pragma unroll
      for (int ps = 0; ps < 4; ++ps) {
        int idx = ps * 256 + tid;
        int row = idx >> 4, c8 = (idx & 15) * 8;
        bf16x8 v = *(const bf16x8*)&bounce[row * 136 + c8];
        int gn = n0 + hh * 64 + row;
        int h = gn >> 6, hd = gn & 63;
        int gmS = m0 + c8;
        int b2 = gmS >> 11, s0 = gmS & 2047;
        *(bf16x8*)&V[(((size_t)(b2 * H_ + h)) * HD_ + hd) * S_ + s0] = v;
      }
    }
  }
}

// ---- out GEMM: 64x128 tile (r11/r12), BK=32, 2-barrier ----
__global__ __launch_bounds__(256) void k_gemm_out(const bf16_t* __restrict__ A,
                                                  const bf16_t* __restrict__ Wp,
                                                  const float* __restrict__ bo,
                                                  float* __restrict__ out) {
  __shared__ bf16_t sA[64 * 32];
  __shared__ bf16_t sB[128 * 32];
  int bid = blockIdx.x;
  int mt = bid & 63, nt = bid >> 6;   // 64 x 8
  int n0 = nt * 128, m0 = mt * 64;
  int tid = threadIdx.x, lane = tid & 63, wave = tid >> 6;
  int wc = wave * 32;
  int crow = lane >> 2, ccol = (lane & 3) * 8;
  const bf16_t* gsrc0; bf16_t* ldst0;
  const bf16_t* gsrc1; bf16_t* ldst1;
  const bf16_t* gsrc2; bf16_t* ldst2;
#pragma unroll
  for (int j = 0; j < 3; ++j) {
    int c = wave * 3 + j;
    const bf16_t* g; bf16_t* l;
    if (c < 4) {
      g = A + (size_t)(m0 + c * 16 + crow) * D_ + ccol;
      l = sA + c * 512;
    } else {
      g = Wp + (size_t)(n0 + (c - 4) * 16 + crow) * D_ + ccol;
      l = sB + (c - 4) * 512;
    }
    if (j == 0) { gsrc0 = g; ldst0 = l; }
    else if (j == 1) { gsrc1 = g; ldst1 = l; }
    else { gsrc2 = g; ldst2 = l; }
  }
  f32x4 acc[4][2] = {};
  int kq = (lane >> 4) * 8, rl = lane & 15, hi = lane >> 4;
  for (int kt = 0; kt < D_; kt += 32) {
    __syncthreads();
    gl_lds16(gsrc0 + kt, ldst0);
    gl_lds16(gsrc1 + kt, ldst1);
    gl_lds16(gsrc2 + kt, ldst2);
    __syncthreads();
    bf16x8 af[4], bfr[2];
#pragma unroll
    for (int m = 0; m < 4; ++m)
      af[m] = *(const bf16x8*)&sA[(m * 16 + rl) * 32 + kq];
#pragma unroll
    for (int n = 0; n < 2; ++n)
      bfr[n] = *(const bf16x8*)&sB[(wc + n * 16 + rl) * 32 + kq];
#pragma unroll
    for (int m = 0; m < 4; ++m)
#pragma unroll
      for (int n = 0; n < 2; ++n)
        acc[m][n] = __builtin_amdgcn_mfma_f32_16x16x32_bf16(af[m], bfr[n], acc[m][n], 0, 0, 0);
  }
#pragma unroll
  for (int m = 0; m < 4; ++m) {
#pragma unroll
    for (int n = 0; n < 2; ++n) {
#pragma unroll
      for (int r = 0; r < 4; ++r) {
        int gm = m0 + m * 16 + hi * 4 + r;
        int gn = n0 + wc + n * 16 + rl;
        out[(size_t)gm * D_ + gn] = acc[m][n][r] + bo[gn];
      }
    }
  }
}

// ---------------- MFMA local causal attention: QB=128, Q direct, 53.5KB LDS ----
#define QB 128
#define KW 160
#define VW 176
#define KLP 68
#define VTP 180

__global__ __launch_bounds__(256) void k_attn(const bf16_t* __restrict__ Q,
                                              const bf16_t* __restrict__ K,
                                              const bf16_t* __restrict__ Vt,
                                              bf16_t* __restrict__ O) {
  __shared__ bf16_t sK[KW][KLP];
  __shared__ bf16_t sV[HD_][VTP];
  __shared__ bf16_t sP[4][16][KLP];
  int bid = blockIdx.x;
  int qb = bid & 15, bh = bid >> 4;
  int q0 = qb * QB;
  const bf16_t* Kp = K + (size_t)bh * S_ * HD_;
  const bf16_t* Vp = Vt + (size_t)bh * HD_ * S_;
  const bf16_t* Qp = Q + (size_t)bh * S_ * HD_;
  int tid = threadIdx.x;
  int lane = tid & 63, wave = tid >> 6;
  int rl = lane & 15, hi = lane >> 4;
  int wk0b = q0 - HW;
  for (int idx = tid; idx < KW * 8; idx += 256) {
    int row = idx >> 3, c8 = (idx & 7) * 8;
    int kg = wk0b + row;
    kg = kg < 0 ? 0 : (kg > S_ - 1 ? S_ - 1 : kg);
    *(bf16x8*)&sK[row][c8] = *(const bf16x8*)(Kp + (size_t)kg * HD_ + c8);
  }
  for (int idx = tid; idx < HD_ * (VW / 8); idx += 256) {
    int row = idx / (VW / 8), c8 = (idx % (VW / 8)) * 8;
    int ks = wk0b + c8;
    ks = ks < 0 ? 0 : (ks > S_ - 8 ? S_ - 8 : ks);
    *(bf16x8*)&sV[row][c8] = *(const bf16x8*)(Vp + (size_t)row * S_ + ks);
  }
  __syncthreads();
  int b = bh >> 4, h = bh & 15;
#pragma unroll
  for (int qi = 0; qi < 2; ++qi) {
    int wko = qi * 64 + wave * 16;
    bf16x8 qf0 = *(const bf16x8*)(Qp + (size_t)(q0 + wko + rl) * HD_ + hi * 8);
    bf16x8 qf1 = *(const bf16x8*)(Qp + (size_t)(q0 + wko + rl) * HD_ + 32 + hi * 8);
    f32x4 accs[3] = {};
#pragma unroll
    for (int kb = 0; kb < 3; ++kb) {
      bf16x8 kf = *(const bf16x8*)&sK[wko + kb * 16 + rl][hi * 8];
      accs[kb] = __builtin_amdgcn_mfma_f32_16x16x32_bf16(kf, qf0, accs[kb], 0, 0, 0);
    }
#pragma unroll
    for (int kb = 0; kb < 3; ++kb) {
      bf16x8 kf = *(const bf16x8*)&sK[wko + kb * 16 + rl][32 + hi * 8];
      accs[kb] = __builtin_amdgcn_mfma_f32_16x16x32_bf16(kf, qf1, accs[kb], 0, 0, 0);
    }
    float p[3][4];
    float mx = -1e30f;
#pragma unroll
    for (int kb = 0; kb < 3; ++kb) {
#pragma unroll
      for (int r = 0; r < 4; ++r) {
        int kl = kb * 16 + hi * 4 + r;
        bool valid = (kl >= rl) && (kl <= rl + HW) && (wk0b + wko + kl >= 0);
        float s = valid ? accs[kb][r] : -1e30f;
        p[kb][r] = s;
        mx = fmaxf(mx, s);
      }
    }
    mx = fmaxf(mx, __shfl_xor(mx, 16));
    mx = fmaxf(mx, __shfl_xor(mx, 32));
    float sum = 0.f;
#pragma unroll
    for (int kb = 0; kb < 3; ++kb)
#pragma unroll
      for (int r = 0; r < 4; ++r) {
        p[kb][r] = __expf(p[kb][r] - mx);
        sum += p[kb][r];
      }
    sum += __shfl_xor(sum, 16);
    sum += __shfl_xor(sum, 32);
    float inv = 1.f / sum;
#pragma unroll
    for (int kb = 0; kb < 3; ++kb) {
      bf16x4 pv;
#pragma unroll
      for (int r = 0; r < 4; ++r) pv[r] = (bf16_t)(p[kb][r] * inv);
      *(bf16x4*)&sP[wave][rl][kb * 16 + hi * 4] = pv;
    }
    {
      bf16x4 z4;
#pragma unroll
      for (int r = 0; r < 4; ++r) z4[r] = (bf16_t)0.f;
      *(bf16x4*)&sP[wave][rl][48 + hi * 4] = z4;   // masked kb=3 slot
    }
    f32x4 acco[4] = {};
#pragma unroll
    for (int ks = 0; ks < 2; ++ks) {
      bf16x8 aP = *(const bf16x8*)&sP[wave][rl][ks * 32 + hi * 8];
#pragma unroll
      for (int n = 0; n < 4; ++n) {
        bf16x8 bV = *(const bf16x8*)&sV[n * 16 + rl][wko + ks * 32 + hi * 8];
        acco[n] = __builtin_amdgcn_mfma_f32_16x16x32_bf16(aP, bV, acco[n], 0, 0, 0);
      }
    }
#pragma unroll
    for (int n = 0; n < 4; ++n) {
#pragma unroll
      for (int r = 0; r < 4; ++r) {
        int qgl = q0 + wko + hi * 4 + r;
        int d = n * 16 + rl;
        O[((size_t)(b * S_ + qgl)) * D_ + h * HD_ + d] = (bf16_t)acco[n][r];
      }
    }
  }
}

extern "C" void kernel_launch(void* const* d_in, const int* in_sizes, int n_in,
                              void* d_out, int out_size, void* d_ws, size_t ws_size,
                              hipStream_t stream) {
  const float* x  = (const float*)d_in[0];
  const float* Wq = (const float*)d_in[1];
  const float* Wk = (const float*)d_in[2];
  const float* Wv = (const float*)d_in[3];
  const float* Wo = (const float*)d_in[4];
  const float* bo = (const float*)d_in[5];
  float* out = (float*)d_out;
  char* ws = (char*)d_ws;
  bf16_t* xb = (bf16_t*)(ws);                       // 8 MB
  bf16_t* wt = (bf16_t*)(ws + (size_t)(8 << 20));   // 8 MB [4][1024][1024]
  bf16_t* qb = (bf16_t*)(ws + (size_t)(16 << 20));  // 8 MB [bh][s][64]
  bf16_t* kb = (bf16_t*)(ws + (size_t)(24 << 20));  // 8 MB [bh][s][64]
  bf16_t* vb = (bf16_t*)(ws + (size_t)(32 << 20));  // 8 MB [bh][64][s] (transposed)
  bf16_t* ob = (bf16_t*)(ws + (size_t)(40 << 20));  // 8 MB [b][s][1024]

  hipLaunchKernelGGL(k_conv, dim3(3072), dim3(256), 0, stream,
                     x, Wq, Wk, Wv, Wo, xb, wt);
  hipLaunchKernelGGL(k_gemm_qkv, dim3(768), dim3(256), 0, stream, xb, wt, qb, kb, vb);
  hipLaunchKernelGGL(k_attn, dim3(512), dim3(256), 0, stream, qb, kb, vb, ob);
  hipLaunchKernelGGL(k_gemm_out, dim3(512), dim3(256), 0, stream,
                     ob, wt + (size_t)3 * D_ * D_, bo, out);
}

// Round 20
// 76.319 us; speedup vs baseline: 1.3300x; 1.0444x over previous
//
#include <hip/hip_runtime.h>
#include <hip/hip_bf16.h>

typedef __bf16 bf16_t;
typedef __bf16 bf16x8 __attribute__((ext_vector_type(8)));
typedef __bf16 bf16x4 __attribute__((ext_vector_type(4)));
typedef float  f32x4  __attribute__((ext_vector_type(4)));

#define B_   2
#define S_   2048
#define D_   1024
#define H_   16
#define HD_  64
#define HW   32
#define SCALE_ 0.125f

__device__ __forceinline__ void gl_lds16(const bf16_t* g, bf16_t* l) {
  __builtin_amdgcn_global_load_lds(
      (const __attribute__((address_space(1))) void*)g,
      (__attribute__((address_space(3))) void*)l, 16, 0, 0);
}

// ------------- fused converts: x fp32->bf16 (blocks 0..2047), W transpose (2048..3071)
__global__ __launch_bounds__(256) void k_conv(const float* __restrict__ X,
                                              const float* __restrict__ W0,
                                              const float* __restrict__ W1,
                                              const float* __restrict__ W2,
                                              const float* __restrict__ W3,
                                              bf16_t* __restrict__ Xb,
                                              bf16_t* __restrict__ Wt) {
  __shared__ bf16_t t[64][72];
  int bid = blockIdx.x;
  int tid = threadIdx.x;
  if (bid < 2048) {
    int i = bid * 256 + tid;
    const float4 a = ((const float4*)X)[i * 2];
    const float4 b = ((const float4*)X)[i * 2 + 1];
    bf16x8 r;
    r[0] = (bf16_t)a.x; r[1] = (bf16_t)a.y; r[2] = (bf16_t)a.z; r[3] = (bf16_t)a.w;
    r[4] = (bf16_t)b.x; r[5] = (bf16_t)b.y; r[6] = (bf16_t)b.z; r[7] = (bf16_t)b.w;
    ((bf16x8*)Xb)[i] = r;
    return;
  }
  int wb = bid - 2048;
  int wsel = wb >> 8;
  const float* W = (wsel == 0) ? W0 : (wsel == 1) ? W1 : (wsel == 2) ? W2 : W3;
  bf16_t* dst = Wt + (size_t)wsel * D_ * D_;
  int tile = wb & 255;
  int k0 = (tile >> 4) * 64, n0 = (tile & 15) * 64;
  int r = tid >> 4, c4 = (tid & 15) * 4;
#pragma unroll
  for (int i = 0; i < 4; ++i) {
    int row = i * 16 + r;
    float4 v = *(const float4*)(W + (size_t)(k0 + row) * D_ + n0 + c4);
    t[row][c4 + 0] = (bf16_t)v.x;
    t[row][c4 + 1] = (bf16_t)v.y;
    t[row][c4 + 2] = (bf16_t)v.z;
    t[row][c4 + 3] = (bf16_t)v.w;
  }
  __syncthreads();
#pragma unroll
  for (int i = 0; i < 4; ++i) {
    int row = i * 16 + r;
    bf16x4 o;
    o[0] = t[c4 + 0][row];
    o[1] = t[c4 + 1][row];
    o[2] = t[c4 + 2][row];
    o[3] = t[c4 + 3][row];
    *(bf16x4*)(dst + (size_t)(n0 + row) * D_ + k0 + c4) = o;
  }
}

// ---- QKV GEMM: r16 loop (128x128, BK=32, triple-buffer counted-vmcnt,
// conflict-free chunk-XOR swizzle) + V-epilogue LDS bounce (coalesced stores).
__global__ __launch_bounds__(256) void k_gemm_qkv(const bf16_t* __restrict__ X,
                                                  const bf16_t* __restrict__ Wt,
                                                  bf16_t* __restrict__ Q,
                                                  bf16_t* __restrict__ Kb,
                                                  bf16_t* __restrict__ V) {
  __shared__ bf16_t sA[3 * 128 * 32];   // 24 KB
  __shared__ bf16_t sB[3 * 128 * 32];   // 24 KB
  int bid = blockIdx.x;
  int mt = bid & 31, nt = bid >> 5;     // XCD = mt%8: 1MB A + 2MB B per XCD L2
  int wsel = nt >> 3;
  int n0 = (nt & 7) * 128, m0 = mt * 128;
  const bf16_t* Wp = Wt + (size_t)wsel * D_ * D_;
  int tid = threadIdx.x, lane = tid & 63, wave = tid >> 6;
  int wr = (wave >> 1) * 64, wc = (wave & 1) * 64;
  int r0 = wave * 32 + (lane >> 2);
  int ce = (((lane & 3) ^ ((lane >> 3) & 3))) * 8;  // pre-swizzled source chunk
  const bf16_t* gA0 = X + (size_t)(m0 + r0) * D_ + ce;
  const bf16_t* gB0 = Wp + (size_t)(n0 + r0) * D_ + ce;
  int lofs = wave * 1024;
#define QSTAGE_(bi, kt) do { \
    gl_lds16(gA0 + (kt), sA + (bi) * 4096 + lofs);        \
    gl_lds16(gA0 + (kt) + (size_t)16 * D_, sA + (bi) * 4096 + lofs + 512); \
    gl_lds16(gB0 + (kt), sB + (bi) * 4096 + lofs);        \
    gl_lds16(gB0 + (kt) + (size_t)16 * D_, sB + (bi) * 4096 + lofs + 512); \
  } while (0)
  f32x4 acc[4][4] = {};
  int rl = lane & 15, hi = lane >> 4;
  int cofs = (hi ^ ((rl >> 1) & 3)) * 8;   // swizzled fragment chunk offset
  QSTAGE_(0, 0);
  QSTAGE_(1, 32);
  asm volatile("s_waitcnt vmcnt(4)" ::: "memory");
  __builtin_amdgcn_sched_barrier(0);
  __builtin_amdgcn_s_barrier();
  asm volatile("" ::: "memory");
  int cur = 0;
  for (int t = 0; t < 32; ++t) {
    const bf16_t* pA = sA + cur * 4096;
    const bf16_t* pB = sB + cur * 4096;
    bf16x8 af[4], bfr[4];
#pragma unroll
    for (int m = 0; m < 4; ++m)
      af[m] = *(const bf16x8*)&pA[(wr + m * 16 + rl) * 32 + cofs];
#pragma unroll
    for (int n = 0; n < 4; ++n)
      bfr[n] = *(const bf16x8*)&pB[(wc + n * 16 + rl) * 32 + cofs];
    int sb = cur + 2; if (sb >= 3) sb -= 3;
    if (t + 2 < 32) QSTAGE_(sb, (t + 2) * 32);
    __builtin_amdgcn_s_setprio(1);
#pragma unroll
    for (int m = 0; m < 4; ++m)
#pragma unroll
      for (int n = 0; n < 4; ++n)
        acc[m][n] = __builtin_amdgcn_mfma_f32_16x16x32_bf16(af[m], bfr[n], acc[m][n], 0, 0, 0);
    __builtin_amdgcn_s_setprio(0);
    if (t < 30) {
      asm volatile("s_waitcnt vmcnt(4)" ::: "memory");
    } else if (t == 30) {
      asm volatile("s_waitcnt vmcnt(0)" ::: "memory");
    }
    if (t < 31) {
      __builtin_amdgcn_sched_barrier(0);
      __builtin_amdgcn_s_barrier();
      asm volatile("" ::: "memory");
    }
    if (++cur == 3) cur = 0;
  }
#undef QSTAGE_
  if (wsel < 2) {
    float qscale = (wsel == 0) ? SCALE_ : 1.0f;
    bf16_t* Dst = wsel ? Kb : Q;
#pragma unroll
    for (int m = 0; m < 4; ++m) {
#pragma unroll
      for (int n = 0; n < 4; ++n) {
#pragma unroll
        for (int r = 0; r < 4; ++r) {
          int gm = m0 + wr + m * 16 + hi * 4 + r;
          int gn = n0 + wc + n * 16 + rl;
          int b = gm >> 11, s = gm & 2047;
          int h = gn >> 6, hd = gn & 63;
          Dst[(((size_t)(b * H_ + h)) * S_ + s) * HD_ + hd] = (bf16_t)(acc[m][n][r] * qscale);
        }
      }
    }
  } else {
    bf16_t* bounce = sA;
#pragma unroll
    for (int hh = 0; hh < 2; ++hh) {
      __syncthreads();
      if ((wave & 1) == hh) {
#pragma unroll
        for (int m = 0; m < 4; ++m)
#pragma unroll
          for (int n = 0; n < 4; ++n)
#pragma unroll
            for (int r = 0; r < 4; ++r)
              bounce[(n * 16 + rl) * 136 + wr + m * 16 + hi * 4 + r] = (bf16_t)acc[m][n][r];
      }
      __syncthreads();
#pragma unroll
      for (int ps = 0; ps < 4; ++ps) {
        int idx = ps * 256 + tid;
        int row = idx >> 4, c8 = (idx & 15) * 8;
        bf16x8 v = *(const bf16x8*)&bounce[row * 136 + c8];
        int gn = n0 + hh * 64 + row;
        int h = gn >> 6, hd = gn & 63;
        int gmS = m0 + c8;
        int b2 = gmS >> 11, s0 = gmS & 2047;
        *(bf16x8*)&V[(((size_t)(b2 * H_ + h)) * HD_ + hd) * S_ + s0] = v;
      }
    }
  }
}

// ---- out GEMM: 64x128, BK=32, ring-3 counted-vmcnt (ported from qkv r16) ----
// 12 chunks/step (A:4, B:8), wave w stages chunks 3w..3w+2 -> vmcnt(3) ledger.
__global__ __launch_bounds__(256) void k_gemm_out(const bf16_t* __restrict__ A,
                                                  const bf16_t* __restrict__ Wp,
                                                  const float* __restrict__ bo,
                                                  float* __restrict__ out) {
  __shared__ bf16_t sA[3 * 64 * 32];    // 12 KB
  __shared__ bf16_t sB[3 * 128 * 32];   // 24 KB
  int bid = blockIdx.x;
  int mt = bid & 63, nt = bid >> 6;   // 64 x 8
  int n0 = nt * 128, m0 = mt * 64;
  int tid = threadIdx.x, lane = tid & 63, wave = tid >> 6;
  int wc = wave * 32;
  int crow = lane >> 2, ccol = (lane & 3) * 8;
  const bf16_t* gsrc0; int isA0, co0;
  const bf16_t* gsrc1; int isA1, co1;
  const bf16_t* gsrc2; int isA2, co2;
#pragma unroll
  for (int j = 0; j < 3; ++j) {
    int c = wave * 3 + j;
    const bf16_t* g; int isA, co;
    if (c < 4) {
      g = A + (size_t)(m0 + c * 16 + crow) * D_ + ccol;
      isA = 1; co = c * 512;
    } else {
      g = Wp + (size_t)(n0 + (c - 4) * 16 + crow) * D_ + ccol;
      isA = 0; co = (c - 4) * 512;
    }
    if (j == 0) { gsrc0 = g; isA0 = isA; co0 = co; }
    else if (j == 1) { gsrc1 = g; isA1 = isA; co1 = co; }
    else { gsrc2 = g; isA2 = isA; co2 = co; }
  }
#define OSTAGE_(bi, kt) do { \
    gl_lds16(gsrc0 + (kt), (isA0 ? sA + (bi) * 2048 : sB + (bi) * 4096) + co0); \
    gl_lds16(gsrc1 + (kt), (isA1 ? sA + (bi) * 2048 : sB + (bi) * 4096) + co1); \
    gl_lds16(gsrc2 + (kt), (isA2 ? sA + (bi) * 2048 : sB + (bi) * 4096) + co2); \
  } while (0)
  f32x4 acc[4][2] = {};
  int kq = (lane >> 4) * 8, rl = lane & 15, hi = lane >> 4;
  OSTAGE_(0, 0);
  OSTAGE_(1, 32);
  asm volatile("s_waitcnt vmcnt(3)" ::: "memory");
  __builtin_amdgcn_sched_barrier(0);
  __builtin_amdgcn_s_barrier();
  asm volatile("" ::: "memory");
  int cur = 0;
  for (int t = 0; t < 32; ++t) {
    const bf16_t* pA = sA + cur * 2048;
    const bf16_t* pB = sB + cur * 4096;
    bf16x8 af[4], bfr[2];
#pragma unroll
    for (int m = 0; m < 4; ++m)
      af[m] = *(const bf16x8*)&pA[(m * 16 + rl) * 32 + kq];
#pragma unroll
    for (int n = 0; n < 2; ++n)
      bfr[n] = *(const bf16x8*)&pB[(wc + n * 16 + rl) * 32 + kq];
    int sb = cur + 2; if (sb >= 3) sb -= 3;
    if (t + 2 < 32) OSTAGE_(sb, (t + 2) * 32);
    __builtin_amdgcn_s_setprio(1);
#pragma unroll
    for (int m = 0; m < 4; ++m)
#pragma unroll
      for (int n = 0; n < 2; ++n)
        acc[m][n] = __builtin_amdgcn_mfma_f32_16x16x32_bf16(af[m], bfr[n], acc[m][n], 0, 0, 0);
    __builtin_amdgcn_s_setprio(0);
    if (t < 30) {
      asm volatile("s_waitcnt vmcnt(3)" ::: "memory");
    } else if (t == 30) {
      asm volatile("s_waitcnt vmcnt(0)" ::: "memory");
    }
    if (t < 31) {
      __builtin_amdgcn_sched_barrier(0);
      __builtin_amdgcn_s_barrier();
      asm volatile("" ::: "memory");
    }
    if (++cur == 3) cur = 0;
  }
#undef OSTAGE_
#pragma unroll
  for (int m = 0; m < 4; ++m) {
#pragma unroll
    for (int n = 0; n < 2; ++n) {
#pragma unroll
      for (int r = 0; r < 4; ++r) {
        int gm = m0 + m * 16 + hi * 4 + r;
        int gn = n0 + wc + n * 16 + rl;
        out[(size_t)gm * D_ + gn] = acc[m][n][r] + bo[gn];
      }
    }
  }
}

// ---------------- MFMA local causal attention: QB=128, Q direct, 53.5KB LDS ----
#define QB 128
#define KW 160
#define VW 176
#define KLP 68
#define VTP 180

__global__ __launch_bounds__(256) void k_attn(const bf16_t* __restrict__ Q,
                                              const bf16_t* __restrict__ K,
                                              const bf16_t* __restrict__ Vt,
                                              bf16_t* __restrict__ O) {
  __shared__ bf16_t sK[KW][KLP];
  __shared__ bf16_t sV[HD_][VTP];
  __shared__ bf16_t sP[4][16][KLP];
  int bid = blockIdx.x;
  int qb = bid & 15, bh = bid >> 4;
  int q0 = qb * QB;
  const bf16_t* Kp = K + (size_t)bh * S_ * HD_;
  const bf16_t* Vp = Vt + (size_t)bh * HD_ * S_;
  const bf16_t* Qp = Q + (size_t)bh * S_ * HD_;
  int tid = threadIdx.x;
  int lane = tid & 63, wave = tid >> 6;
  int rl = lane & 15, hi = lane >> 4;
  int wk0b = q0 - HW;
  for (int idx = tid; idx < KW * 8; idx += 256) {
    int row = idx >> 3, c8 = (idx & 7) * 8;
    int kg = wk0b + row;
    kg = kg < 0 ? 0 : (kg > S_ - 1 ? S_ - 1 : kg);
    *(bf16x8*)&sK[row][c8] = *(const bf16x8*)(Kp + (size_t)kg * HD_ + c8);
  }
  for (int idx = tid; idx < HD_ * (VW / 8); idx += 256) {
    int row = idx / (VW / 8), c8 = (idx % (VW / 8)) * 8;
    int ks = wk0b + c8;
    ks = ks < 0 ? 0 : (ks > S_ - 8 ? S_ - 8 : ks);
    *(bf16x8*)&sV[row][c8] = *(const bf16x8*)(Vp + (size_t)row * S_ + ks);
  }
  __syncthreads();
  int b = bh >> 4, h = bh & 15;
#pragma unroll
  for (int qi = 0; qi < 2; ++qi) {
    int wko = qi * 64 + wave * 16;
    bf16x8 qf0 = *(const bf16x8*)(Qp + (size_t)(q0 + wko + rl) * HD_ + hi * 8);
    bf16x8 qf1 = *(const bf16x8*)(Qp + (size_t)(q0 + wko + rl) * HD_ + 32 + hi * 8);
    f32x4 accs[3] = {};
#pragma unroll
    for (int kb = 0; kb < 3; ++kb) {
      bf16x8 kf = *(const bf16x8*)&sK[wko + kb * 16 + rl][hi * 8];
      accs[kb] = __builtin_amdgcn_mfma_f32_16x16x32_bf16(kf, qf0, accs[kb], 0, 0, 0);
    }
#pragma unroll
    for (int kb = 0; kb < 3; ++kb) {
      bf16x8 kf = *(const bf16x8*)&sK[wko + kb * 16 + rl][32 + hi * 8];
      accs[kb] = __builtin_amdgcn_mfma_f32_16x16x32_bf16(kf, qf1, accs[kb], 0, 0, 0);
    }
    float p[3][4];
    float mx = -1e30f;
#pragma unroll
    for (int kb = 0; kb < 3; ++kb) {
#pragma unroll
      for (int r = 0; r < 4; ++r) {
        int kl = kb * 16 + hi * 4 + r;
        bool valid = (kl >= rl) && (kl <= rl + HW) && (wk0b + wko + kl >= 0);
        float s = valid ? accs[kb][r] : -1e30f;
        p[kb][r] = s;
        mx = fmaxf(mx, s);
      }
    }
    mx = fmaxf(mx, __shfl_xor(mx, 16));
    mx = fmaxf(mx, __shfl_xor(mx, 32));
    float sum = 0.f;
#pragma unroll
    for (int kb = 0; kb < 3; ++kb)
#pragma unroll
      for (int r = 0; r < 4; ++r) {
        p[kb][r] = __expf(p[kb][r] - mx);
        sum += p[kb][r];
      }
    sum += __shfl_xor(sum, 16);
    sum += __shfl_xor(sum, 32);
    float inv = 1.f / sum;
#pragma unroll
    for (int kb = 0; kb < 3; ++kb) {
      bf16x4 pv;
#pragma unroll
      for (int r = 0; r < 4; ++r) pv[r] = (bf16_t)(p[kb][r] * inv);
      *(bf16x4*)&sP[wave][rl][kb * 16 + hi * 4] = pv;
    }
    {
      bf16x4 z4;
#pragma unroll
      for (int r = 0; r < 4; ++r) z4[r] = (bf16_t)0.f;
      *(bf16x4*)&sP[wave][rl][48 + hi * 4] = z4;
    }
    f32x4 acco[4] = {};
#pragma unroll
    for (int ks = 0; ks < 2; ++ks) {
      bf16x8 aP = *(const bf16x8*)&sP[wave][rl][ks * 32 + hi * 8];
#pragma unroll
      for (int n = 0; n < 4; ++n) {
        bf16x8 bV = *(const bf16x8*)&sV[n * 16 + rl][wko + ks * 32 + hi * 8];
        acco[n] = __builtin_amdgcn_mfma_f32_16x16x32_bf16(aP, bV, acco[n], 0, 0, 0);
      }
    }
#pragma unroll
    for (int n = 0; n < 4; ++n) {
#pragma unroll
      for (int r = 0; r < 4; ++r) {
        int qgl = q0 + wko + hi * 4 + r;
        int d = n * 16 + rl;
        O[((size_t)(b * S_ + qgl)) * D_ + h * HD_ + d] = (bf16_t)acco[n][r];
      }
    }
  }
}

extern "C" void kernel_launch(void* const* d_in, const int* in_sizes, int n_in,
                              void* d_out, int out_size, void* d_ws, size_t ws_size,
                              hipStream_t stream) {
  const float* x  = (const float*)d_in[0];
  const float* Wq = (const float*)d_in[1];
  const float* Wk = (const float*)d_in[2];
  const float* Wv = (const float*)d_in[3];
  const float* Wo = (const float*)d_in[4];
  const float* bo = (const float*)d_in[5];
  float* out = (float*)d_out;
  char* ws = (char*)d_ws;
  bf16_t* xb = (bf16_t*)(ws);                       // 8 MB
  bf16_t* wt = (bf16_t*)(ws + (size_t)(8 << 20));   // 8 MB [4][1024][1024]
  bf16_t* qb = (bf16_t*)(ws + (size_t)(16 << 20));  // 8 MB [bh][s][64]
  bf16_t* kb = (bf16_t*)(ws + (size_t)(24 << 20));  // 8 MB [bh][s][64]
  bf16_t* vb = (bf16_t*)(ws + (size_t)(32 << 20));  // 8 MB [bh][64][s] (transposed)
  bf16_t* ob = (bf16_t*)(ws + (size_t)(40 << 20));  // 8 MB [b][s][1024]

  hipLaunchKernelGGL(k_conv, dim3(3072), dim3(256), 0, stream,
                     x, Wq, Wk, Wv, Wo, xb, wt);
  hipLaunchKernelGGL(k_gemm_qkv, dim3(768), dim3(256), 0, stream, xb, wt, qb, kb, vb);
  hipLaunchKernelGGL(k_attn, dim3(512), dim3(256), 0, stream, qb, kb, vb, ob);
  hipLaunchKernelGGL(k_gemm_out, dim3(512), dim3(256), 0, stream,
                     ob, wt + (size_t)3 * D_ * D_, bo, out);
}